// Round 3
// baseline (870.271 us; speedup 1.0000x reference)
//
#include <hip/hip_runtime.h>
#include <math.h>

typedef unsigned short u16;
typedef __bf16 bf16x8 __attribute__((ext_vector_type(8)));
typedef float  f32x4  __attribute__((ext_vector_type(4)));

__device__ __forceinline__ u16 f2bf(float f) {
    unsigned int u = __float_as_uint(f);
    u = (u + 0x7FFFu + ((u >> 16) & 1u)) >> 16;   // RNE
    return (u16)u;
}

union bfpack { bf16x8 v; u16 h[8]; };

// ---------------------------------------------------------------------------
// Batched transpose + fp32->bf16 convert: src fp32 [G][K][N] -> dst bf16 [G][N][K]
// grid: (N/32, K/32, G), block 256
// ---------------------------------------------------------------------------
__global__ void transpose_k(const float* __restrict__ src, u16* __restrict__ dst,
                            int K, int N) {
    __shared__ u16 tile[32][33];
    long g = blockIdx.z;
    const float* s = src + g * (long)K * N;
    u16* d = dst + g * (long)K * N;
    int n0 = blockIdx.x * 32, k0 = blockIdx.y * 32;
    int tx = threadIdx.x & 31, ty = threadIdx.x >> 5;   // ty 0..7
#pragma unroll
    for (int r = ty; r < 32; r += 8)
        tile[r][tx] = f2bf(s[(long)(k0 + r) * N + n0 + tx]);
    __syncthreads();
#pragma unroll
    for (int r = ty; r < 32; r += 8)
        d[(long)(n0 + r) * K + k0 + tx] = tile[tx][r];
}

// ---------------------------------------------------------------------------
// Grouped GEMM: C[g] = act(A[g] @ W[g] + b[g])
//   A: bf16 (a_fp32=0) or fp32 (a_fp32=1); element (g,m,i) at A + g*strideAn + m*lda + i
//   Wt: bf16 [G][N][K] (pre-transposed+converted)
//   bias: fp32 [G][N]
//   C: bf16 (c_fp32=0) or fp32 (c_fp32=1); element (g,m,n) at C + g*strideCn + m*ldc + n
// Tile: 128(M) x 128(N) x 32(K), 4 waves (2x2), 16x16x32 bf16 MFMA.
// act: 0=none 1=relu 2=tanh
// grid: ((N+127)/128, M/128, G), block 256
// ---------------------------------------------------------------------------
__global__ __launch_bounds__(256, 2)
void gemm_fnn(const void* __restrict__ A, int a_fp32, long strideAn, int lda,
              const u16* __restrict__ Wt, const float* __restrict__ bias,
              void* __restrict__ C, int c_fp32, long strideCn, int ldc,
              int K, int N, int act)
{
    __shared__ __align__(16) u16 As[128 * 32];
    __shared__ __align__(16) u16 Bs[128 * 32];

    const int g  = blockIdx.z;
    const int m0 = blockIdx.y * 128;
    const int n0 = blockIdx.x * 128;

    const u16* Wg = Wt + (long)g * K * N;
    const float* bg = bias + (long)g * N;

    const int tid  = threadIdx.x;
    const int lane = tid & 63;
    const int wv   = tid >> 6;      // 0..3
    const int wm   = wv & 1;        // row half (M)
    const int wn   = wv >> 1;       // col half (N)
    const int lr   = lane & 15;
    const int lq   = lane >> 4;

    f32x4 acc[4][4] = {};

    // staging: 128 rows x 32 k; per thread 2 granules of 8 elements
    const int row0 = tid >> 2;            // 0..63
    const int c8   = (tid & 3) * 8;       // 0,8,16,24

    for (int k0 = 0; k0 < K; k0 += 32) {
        bf16x8 av[2], bv[2];
        if (a_fp32) {
            const float* Af = (const float*)A + (long)g * strideAn;
#pragma unroll
            for (int r = 0; r < 2; ++r) {
                int row = r * 64 + row0;
                const float* gp = Af + (long)(m0 + row) * lda + k0 + c8;
                float4 x0 = *(const float4*)gp;
                float4 x1 = *(const float4*)(gp + 4);
                bfpack p;
                p.h[0] = f2bf(x0.x); p.h[1] = f2bf(x0.y);
                p.h[2] = f2bf(x0.z); p.h[3] = f2bf(x0.w);
                p.h[4] = f2bf(x1.x); p.h[5] = f2bf(x1.y);
                p.h[6] = f2bf(x1.z); p.h[7] = f2bf(x1.w);
                av[r] = p.v;
            }
        } else {
            const u16* Ab = (const u16*)A + (long)g * strideAn;
#pragma unroll
            for (int r = 0; r < 2; ++r) {
                int row = r * 64 + row0;
                av[r] = *(const bf16x8*)(Ab + (long)(m0 + row) * lda + k0 + c8);
            }
        }
#pragma unroll
        for (int r = 0; r < 2; ++r) {
            int row = r * 64 + row0;
            int nr = n0 + row; if (nr > N - 1) nr = N - 1;   // clamp (N=32 tail)
            bv[r] = *(const bf16x8*)(Wg + (long)nr * K + k0 + c8);
        }
#pragma unroll
        for (int r = 0; r < 2; ++r) {
            int row = r * 64 + row0;
            *(bf16x8*)&As[row * 32 + c8] = av[r];
            *(bf16x8*)&Bs[row * 32 + c8] = bv[r];
        }
        __syncthreads();

        bf16x8 af[4], bw[4];
#pragma unroll
        for (int i = 0; i < 4; ++i)
            af[i] = *(const bf16x8*)&As[(wm * 64 + i * 16 + lr) * 32 + lq * 8];
#pragma unroll
        for (int j = 0; j < 4; ++j)
            bw[j] = *(const bf16x8*)&Bs[(wn * 64 + j * 16 + lr) * 32 + lq * 8];
#pragma unroll
        for (int i = 0; i < 4; ++i)
#pragma unroll
            for (int j = 0; j < 4; ++j)
                acc[i][j] = __builtin_amdgcn_mfma_f32_16x16x32_bf16(
                    af[i], bw[j], acc[i][j], 0, 0, 0);
        __syncthreads();
    }

    // ---- epilogue: C/D layout col=lane&15, row=(lane>>4)*4+reg
#pragma unroll
    for (int j = 0; j < 4; ++j) {
        int n = n0 + wn * 64 + j * 16 + lr;
        if (n >= N) continue;
        float bvs = bg[n];
#pragma unroll
        for (int i = 0; i < 4; ++i) {
            int mb = m0 + wm * 64 + i * 16 + lq * 4;
#pragma unroll
            for (int r = 0; r < 4; ++r) {
                float v = acc[i][j][r] + bvs;
                if (act == 1) v = fmaxf(v, 0.f);
                else if (act == 2) v = tanhf(v);
                long idx = (long)g * strideCn + (long)(mb + r) * ldc + n;
                if (c_fp32) ((float*)C)[idx] = v;
                else        ((u16*)C)[idx]  = f2bf(v);
            }
        }
    }
}

// ---------------------------------------------------------------------------
extern "C" void kernel_launch(void* const* d_in, const int* in_sizes, int n_in,
                              void* d_out, int out_size, void* d_ws, size_t ws_size,
                              hipStream_t stream) {
    const int B = 4096, S = 256, D = 128, NA = 32, CD = 512;

    const float* state   = (const float*)d_in[0];
    const float* enc_w1  = (const float*)d_in[1];
    const float* enc_b1  = (const float*)d_in[2];
    const float* enc_wh  = (const float*)d_in[3];
    const float* enc_bh  = (const float*)d_in[4];
    const float* enc_wo  = (const float*)d_in[5];
    const float* enc_bo  = (const float*)d_in[6];
    const float *agg_w1[3], *agg_b1[3], *agg_wh[3], *agg_bh[3], *agg_wo[3], *agg_bo[3];
    for (int l = 0; l < 3; ++l) {
        agg_w1[l] = (const float*)d_in[7 + 6 * l + 0];
        agg_b1[l] = (const float*)d_in[7 + 6 * l + 1];
        agg_wh[l] = (const float*)d_in[7 + 6 * l + 2];
        agg_bh[l] = (const float*)d_in[7 + 6 * l + 3];
        agg_wo[l] = (const float*)d_in[7 + 6 * l + 4];
        agg_bo[l] = (const float*)d_in[7 + 6 * l + 5];
    }
    const float* head_w1 = (const float*)d_in[25];
    const float* head_b1 = (const float*)d_in[26];
    const float* head_wh = (const float*)d_in[27];
    const float* head_bh = (const float*)d_in[28];
    const float* head_wo = (const float*)d_in[29];
    const float* head_bo = (const float*)d_in[30];

    float* out    = (float*)d_out;               // embeds [B][85][128] fp32
    float* action = out + (long)B * 85 * D;      // [B][32] fp32

    // ---- carve workspace (bf16 elements)
    char* wsp = (char*)d_ws;
    auto carve = [&](long elems) {
        u16* p = (u16*)wsp;
        wsp += ((elems * 2 + 255) / 256) * 256;
        return p;
    };
    u16* enc_w1t = carve(64L * 128 * 256);
    u16* enc_wht = carve(64L * 128 * 128);
    u16* enc_wot = carve(64L * 128 * 128);
    u16 *agg_w1t[3], *agg_wht[3], *agg_wot[3];
    const int LN[3] = {16, 4, 1};
    for (int l = 0; l < 3; ++l) {
        agg_w1t[l] = carve((long)LN[l] * 512 * 512);
        agg_wht[l] = carve((long)LN[l] * 512 * 512);
        agg_wot[l] = carve((long)LN[l] * 128 * 512);
    }
    u16* head_w1t = carve(128L * 128);
    u16* head_wht = carve(128L * 128);
    u16* head_wot = carve(32L * 128);
    u16* bufA = carve(33554432L);   // bf16 activations: max 16*B*512 = 64*B*128
    u16* bufB = carve(33554432L);

    // ---- weight transposes+convert: fp32 [G][K][N] -> bf16 [G][N][K]
    auto T = [&](const float* src, u16* dst, int G, int K, int N) {
        dim3 gr(N / 32, K / 32, G);
        transpose_k<<<gr, 256, 0, stream>>>(src, dst, K, N);
    };
    T(enc_w1, enc_w1t, 64, 256, 128);
    T(enc_wh, enc_wht, 64, 128, 128);
    T(enc_wo, enc_wot, 64, 128, 128);
    for (int l = 0; l < 3; ++l) {
        T(agg_w1[l], agg_w1t[l], LN[l], 512, 512);
        T(agg_wh[l], agg_wht[l], LN[l], 512, 512);
        T(agg_wo[l], agg_wot[l], LN[l], 512, 128);
    }
    T(head_w1, head_w1t, 1, 128, 128);
    T(head_wh, head_wht, 1, 128, 128);
    T(head_wo, head_wot, 1, 128, 32);

    // ---- grouped GEMM launcher
    auto G = [&](const void* Ap, int a_fp32, long sAn, int lda,
                 const u16* Wt, const float* bias,
                 void* Cp, int c_fp32, long sCn, int ldc,
                 int K, int N, int act, int groups) {
        dim3 gr((N + 127) / 128, B / 128, groups);
        gemm_fnn<<<gr, 256, 0, stream>>>(Ap, a_fp32, sAn, lda, Wt, bias,
                                         Cp, c_fp32, sCn, ldc, K, N, act);
    };
    const int LD_OUT = 85 * D;   // 10880

    // encoders: state [B,S] fp32 shared across 64 groups
    G(state, 1, 0, S, enc_w1t, enc_b1, bufA, 0, (long)B * D, D, S, D, 1, 64);
    G(bufA, 0, (long)B * D, D, enc_wht, enc_bh, bufB, 0, (long)B * D, D, D, D, 1, 64);
    G(bufB, 0, (long)B * D, D, enc_wot, enc_bo, out, 1, D, LD_OUT, D, D, 0, 64);

    // aggregator levels: input = contiguous 4-node slice of embeds (fp32 in d_out)
    const int tbase[3] = {0, 64, 80};
    const int tout[3]  = {64, 80, 84};
    for (int l = 0; l < 3; ++l) {
        int n = LN[l];
        G(out + (long)tbase[l] * D, 1, 4L * D, LD_OUT, agg_w1t[l], agg_b1[l],
          bufA, 0, (long)B * CD, CD, CD, CD, 1, n);
        G(bufA, 0, (long)B * CD, CD, agg_wht[l], agg_bh[l],
          bufB, 0, (long)B * CD, CD, CD, CD, 1, n);
        G(bufB, 0, (long)B * CD, CD, agg_wot[l], agg_bo[l],
          out + (long)tout[l] * D, 1, D, LD_OUT, CD, D, 0, n);
    }

    // head: root = embeds t=84 (fp32)
    G(out + 84L * D, 1, 0, LD_OUT, head_w1t, head_b1, bufA, 0, 0, D, D, D, 1, 1);
    G(bufA, 0, 0, D, head_wht, head_bh, bufB, 0, 0, D, D, D, 1, 1);
    G(bufB, 0, 0, D, head_wot, head_bo, action, 1, 0, NA, D, NA, 2, 1);
}